// Round 1
// baseline (393.030 us; speedup 1.0000x reference)
//
#include <hip/hip_runtime.h>
#include <stdint.h>

#define S_DIM 8192
#define K_DIM 4096
#define N_DIM 4096

#define BM 256
#define BN 256
#define BKB 64                // bytes of K per pipeline tile (one 16x16x64 k-step)
#define NT (K_DIM / BKB)      // 64 K-tiles

typedef int v4i __attribute__((ext_vector_type(4)));

// ---------------------------------------------------------------------------
// One launch: pack x (int32->int8), pack w, and copy scale_y to the output
// tail. Pack destination is contiguous in ws: [x packed | w packed].
__global__ void prep(const int* __restrict__ x, const int* __restrict__ w,
                     const float* __restrict__ sy,
                     int* __restrict__ dst, float* __restrict__ out) {
    const int nx = S_DIM * K_DIM / 4;
    const int nw = N_DIM * K_DIM / 4;
    int i = blockIdx.x * 256 + threadIdx.x;
    if (i < nx) {
        int4 a = ((const int4*)x)[i];
        dst[i] = (a.x & 0xFF) | ((a.y & 0xFF) << 8) | ((a.z & 0xFF) << 16)
               | ((a.w & 0xFF) << 24);
    } else if (i < nx + nw) {
        int4 a = ((const int4*)w)[i - nx];
        dst[i] = (a.x & 0xFF) | ((a.y & 0xFF) << 8) | ((a.z & 0xFF) << 16)
               | ((a.w & 0xFF) << 24);
    } else {
        int j = i - nx - nw;
        if (j < S_DIM) out[(size_t)S_DIM * N_DIM + j] = sy[j];
    }
}

// scale_y tail only (used by the no-workspace fallback path)
__global__ void copy_sy(const float* __restrict__ sy, float* __restrict__ out) {
    int i = blockIdx.x * blockDim.x + threadIdx.x;
    if (i < S_DIM) out[(size_t)S_DIM * N_DIM + i] = sy[i];
}

// ---------------------------------------------------------------------------
__device__ __forceinline__ void g2lds16(const void* g, void* l) {
    __builtin_amdgcn_global_load_lds((const __attribute__((address_space(1))) void*)g,
                                     (__attribute__((address_space(3))) void*)l,
                                     16, 0, 0);
}

// ---------------------------------------------------------------------------
// 256x256 tile i8 MFMA GEMM, phased-pipeline schedule (T3+T4+T5 on top of the
// verified T2 swizzle):
//  - 8 waves (2M x 4N); each wave owns 128x64 output = 8x4 tiles of
//    mfma_i32_16x16x64_i8 (acc = 128 VGPR).
//  - K is cut into 64-byte tiles held in a 4-deep LDS ring (4 x 32 KB =
//    128 KiB). Tile t+3 is staged (global_load_lds w=16) while tile t
//    computes -> 3 tiles of prefetch in flight.
//  - Raw s_barrier (NOT __syncthreads: that would emit vmcnt(0) and drain the
//    load queue every tile). Visibility is per-wave s_waitcnt vmcnt(8) once
//    per tile: leaves the newest 8 loads (tiles t+2,t+3) in flight, proves
//    tile t+1 landed. Drain ladder 8->4->0 over the last 3 tiles.
//  - 2 phases/tile: {frag ds_reads + stage issue; barrier; lgkmcnt(0);
//    setprio(1); 16 MFMA; setprio(0); barrier}.
// LDS layout: per operand tile = 256 rows x 64 B = 1024 16B chunks. Rows are
// paired into 128-B super-rows; chunk position p (0..7) in super-row s sits at
// slot p ^ (s&7). Fragment ds_read_b128 then sweeps each super-row's 8 slots
// with a full-permutation -> all 32 banks exactly once per super-row ->
// conflict-free (same algebra as the verified 128-B-row swizzle). Staging
// writes the LDS linearly (global_load_lds constraint) with the INVERSE
// permutation applied to the per-lane global source address.
__launch_bounds__(512, 2)
__global__ void gemm_i8(const signed char* __restrict__ xp,
                        const signed char* __restrict__ wp,
                        const float* __restrict__ sx,
                        const float* __restrict__ sw,
                        const float* __restrict__ sy,
                        float* __restrict__ out) {
    __shared__ __align__(16) signed char As[4][BM * BKB];   // 64 KB
    __shared__ __align__(16) signed char Bs[4][BN * BKB];   // 64 KB

    const int tid  = threadIdx.x;      // 0..511
    const int lane = tid & 63;
    const int quad = lane >> 4;        // 16B k-chunk within the 64B k-step
    const int l16  = lane & 15;        // row (A) / col (B) within 16
    const int wave = tid >> 6;         // 0..7
    const int wm = wave >> 2;          // 0..1 -> 128-row slab
    const int wn = wave & 3;           // 0..3 -> 64-col slab
    const int bn = blockIdx.x;
    const int bm = blockIdx.y;

    const signed char* aG = xp + (size_t)(bm * BM) * K_DIM;
    const signed char* bG = wp + (size_t)(bn * BN) * K_DIM;

    // Staging source offsets: thread handles linear LDS chunks tid and
    // 512+tid of each operand tile. For LDS chunk L: super-row s=L>>3,
    // slot=L&7, p=slot^(s&7), row=2s+(p>>2), kchunk=p&3.
    int gOff0, gOff1;
    {
        int L = tid;
        int s = L >> 3, sl = L & 7, p = sl ^ (s & 7);
        gOff0 = (2 * s + (p >> 2)) * K_DIM + ((p & 3) << 4);
        L = 512 + tid;
        s = L >> 3; sl = L & 7; p = sl ^ (s & 7);
        gOff1 = (2 * s + (p >> 2)) * K_DIM + ((p & 3) << 4);
    }

    // Fragment read offset for (row = base + l16, chunk = quad):
    // byte = (row>>1)*128 + ((((row&1)<<2)|quad) ^ ((row>>1)&7))*16, with the
    // base (multiple of 16) contributing base*64 separately.
    const int rdo = ((l16 >> 1) * 128)
                  + (((((l16 & 1) << 2) | quad) ^ ((l16 >> 1) & 7)) << 4);

#define STAGE_A(T) do { const int kk_ = (T) * BKB;                          \
        signed char* d_ = &As[(T) & 3][0];                                  \
        g2lds16(aG + gOff0 + kk_, d_ + tid * 16);                           \
        g2lds16(aG + gOff1 + kk_, d_ + 8192 + tid * 16); } while (0)
#define STAGE_B(T) do { const int kk_ = (T) * BKB;                          \
        signed char* d_ = &Bs[(T) & 3][0];                                  \
        g2lds16(bG + gOff0 + kk_, d_ + tid * 16);                           \
        g2lds16(bG + gOff1 + kk_, d_ + 8192 + tid * 16); } while (0)

    v4i acc[8][4];
#pragma unroll
    for (int i = 0; i < 8; i++)
#pragma unroll
        for (int j = 0; j < 4; j++) acc[i][j] = 0;

    // Prologue: stage tiles 0,1,2 (12 loads/thread); prove tile 0 landed.
    STAGE_A(0); STAGE_B(0);
    STAGE_A(1); STAGE_B(1);
    STAGE_A(2); STAGE_B(2);
    asm volatile("s_waitcnt vmcnt(8)" ::: "memory");
    __builtin_amdgcn_s_barrier();

    for (int t = 0; t < NT; ++t) {
        const signed char* a_lds = &As[t & 3][0] + wm * (128 * 64) + rdo;
        const signed char* b_lds = &Bs[t & 3][0] + wn * (64 * 64) + rdo;

        // ---- phase 0: A frags mt 0..3 + all B frags; stage A of t+3 ----
        v4i a0[4], bf[4];
#pragma unroll
        for (int mt = 0; mt < 4; mt++)
            a0[mt] = *(const v4i*)(a_lds + mt * 1024);
#pragma unroll
        for (int nt = 0; nt < 4; nt++)
            bf[nt] = *(const v4i*)(b_lds + nt * 1024);
        if (t + 3 < NT) STAGE_A(t + 3);
        __builtin_amdgcn_s_barrier();
        asm volatile("s_waitcnt lgkmcnt(0)" ::: "memory");
        __builtin_amdgcn_sched_barrier(0);
        __builtin_amdgcn_s_setprio(1);
#pragma unroll
        for (int mt = 0; mt < 4; mt++)
#pragma unroll
            for (int nt = 0; nt < 4; nt++)
                acc[mt][nt] = __builtin_amdgcn_mfma_i32_16x16x64_i8(
                    a0[mt], bf[nt], acc[mt][nt], 0, 0, 0);
        __builtin_amdgcn_s_setprio(0);
        __builtin_amdgcn_s_barrier();

        // ---- phase 1: A frags mt 4..7 (B reused); stage B of t+3 ----
        v4i a1[4];
#pragma unroll
        for (int mt = 0; mt < 4; mt++)
            a1[mt] = *(const v4i*)(a_lds + (4 + mt) * 1024);
        if (t + 3 < NT) STAGE_B(t + 3);
        // Counted vmcnt: after issuing B(t+3), the 8 newest outstanding loads
        // are tiles t+2,t+3 -> this proves tile t+1 is fully in LDS.
        if (t < NT - 3)       asm volatile("s_waitcnt vmcnt(8)" ::: "memory");
        else if (t == NT - 3) asm volatile("s_waitcnt vmcnt(4)" ::: "memory");
        else                  asm volatile("s_waitcnt vmcnt(0)" ::: "memory");
        __builtin_amdgcn_s_barrier();
        asm volatile("s_waitcnt lgkmcnt(0)" ::: "memory");
        __builtin_amdgcn_sched_barrier(0);
        __builtin_amdgcn_s_setprio(1);
#pragma unroll
        for (int mt = 0; mt < 4; mt++)
#pragma unroll
            for (int nt = 0; nt < 4; nt++)
                acc[4 + mt][nt] = __builtin_amdgcn_mfma_i32_16x16x64_i8(
                    a1[mt], bf[nt], acc[4 + mt][nt], 0, 0, 0);
        __builtin_amdgcn_s_setprio(0);
        __builtin_amdgcn_s_barrier();
    }
#undef STAGE_A
#undef STAGE_B

    // Epilogue: C/D layout: col = lane&15, row = quad*4 + reg.
    const int s_base = bm * BM + wm * 128;
    const int n_base = bn * BN + wn * 64;
    float swv[4];
#pragma unroll
    for (int nt = 0; nt < 4; nt++) swv[nt] = sw[n_base + nt * 16 + l16];
#pragma unroll
    for (int mt = 0; mt < 8; mt++) {
#pragma unroll
        for (int r = 0; r < 4; r++) {
            int s = s_base + mt * 16 + quad * 4 + r;
            float rs = sx[s] / sy[s];
            float* orow = out + (size_t)s * N_DIM;
#pragma unroll
            for (int nt = 0; nt < 4; nt++) {
                int n = n_base + nt * 16 + l16;
                float v = rintf((float)acc[mt][nt][r] * (rs * swv[nt]));
                v = fminf(fmaxf(v, -128.f), 127.f);
                orow[n] = v;
            }
        }
    }
}

// ---------------------------------------------------------------------------
// Correctness fallback if the workspace is too small for packed operands.
__global__ void gemm_naive(const int* __restrict__ x, const int* __restrict__ w,
                           const float* __restrict__ sx, const float* __restrict__ sw,
                           const float* __restrict__ sy, float* __restrict__ out) {
    int n = blockIdx.x * blockDim.x + threadIdx.x;
    int s = blockIdx.y;
    const int4* xr = (const int4*)(x + (size_t)s * K_DIM);
    const int4* wr = (const int4*)(w + (size_t)n * K_DIM);
    int acc = 0;
    for (int k = 0; k < K_DIM / 4; k++) {
        int4 a = xr[k], b = wr[k];
        acc += a.x * b.x + a.y * b.y + a.z * b.z + a.w * b.w;
    }
    float v = rintf((float)acc * (sx[s] / sy[s] * sw[n]));
    out[(size_t)s * N_DIM + n] = fminf(fmaxf(v, -128.f), 127.f);
}

// ---------------------------------------------------------------------------
extern "C" void kernel_launch(void* const* d_in, const int* in_sizes, int n_in,
                              void* d_out, int out_size, void* d_ws, size_t ws_size,
                              hipStream_t stream) {
    const int*   x  = (const int*)d_in[0];     // [S, K] int8 values widened to int32
    const int*   wq = (const int*)d_in[1];     // [N, K]
    const float* sx = (const float*)d_in[2];   // [S]
    const float* sw = (const float*)d_in[3];   // [N]
    const float* sy = (const float*)d_in[4];   // [S]
    float* out = (float*)d_out;                // [S*N out_q] ++ [S scale_y], float32

    const size_t need = (size_t)S_DIM * K_DIM + (size_t)N_DIM * K_DIM;  // 48 MiB
    if (ws_size >= need) {
        signed char* xp = (signed char*)d_ws;
        signed char* wp = xp + (size_t)S_DIM * K_DIM;
        const int nprep = (S_DIM * K_DIM / 4) + (N_DIM * K_DIM / 4) + S_DIM;
        prep<<<dim3((nprep + 255) / 256), dim3(256), 0, stream>>>(
            x, wq, sy, (int*)xp, out);
        gemm_i8<<<dim3(N_DIM / BN, S_DIM / BM), dim3(512), 0, stream>>>(
            xp, wp, sx, sw, sy, out);
    } else {
        copy_sy<<<dim3((S_DIM + 255) / 256), dim3(256), 0, stream>>>(sy, out);
        gemm_naive<<<dim3(N_DIM / 256, S_DIM), dim3(256), 0, stream>>>(
            x, wq, sx, sw, sy, out);
    }
}